// Round 1
// baseline (8149.603 us; speedup 1.0000x reference)
//
#include <hip/hip_runtime.h>
#include <hip/hip_bf16.h>

// Problem constants (match reference)
#define USER_COUNT 100000
#define ITEM_COUNT 50000
#define N_NODES    (USER_COUNT + ITEM_COUNT)   // 150000
#define EMB        128
#define N_LAYERS   3
#define NNZ        1600000
#define BATCH      4096

// ---------------------------------------------------------------------------
// Layer-0 gather: out = 0.25 * concat(user_emb,item_emb)[sel rows]
// out layout: [user_out (4096x128) ; item_out (4096x128)], fp32.
// One thread per float4: BATCH*2 rows * 32 lanes.
// ---------------------------------------------------------------------------
__global__ void gather_init(const float* __restrict__ user_emb,
                            const float* __restrict__ item_emb,
                            const int*   __restrict__ users,
                            const int*   __restrict__ items,
                            float* __restrict__ out)
{
    int gid = blockIdx.x * blockDim.x + threadIdx.x;   // [0, 2*BATCH*32)
    int b = gid >> 5;          // output row
    int j = (gid & 31) * 4;    // feature offset
    if (b >= 2 * BATCH) return;
    const float* src;
    if (b < BATCH) {
        src = user_emb + (long long)users[b] * EMB;
    } else {
        src = item_emb + (long long)items[b - BATCH] * EMB;
    }
    float4 v = *(const float4*)(src + j);
    float4 o;
    o.x = 0.25f * v.x; o.y = 0.25f * v.y; o.z = 0.25f * v.z; o.w = 0.25f * v.w;
    *(float4*)(out + (long long)b * EMB + j) = o;
}

// ---------------------------------------------------------------------------
// Gather-accumulate: out += 0.25 * src[sel rows]
// ---------------------------------------------------------------------------
__global__ void gather_acc(const float* __restrict__ src,
                           const int*   __restrict__ users,
                           const int*   __restrict__ items,
                           float* __restrict__ out)
{
    int gid = blockIdx.x * blockDim.x + threadIdx.x;
    int b = gid >> 5;
    int j = (gid & 31) * 4;
    if (b >= 2 * BATCH) return;
    long long node;
    if (b < BATCH) node = users[b];
    else           node = USER_COUNT + (long long)items[b - BATCH];
    float4 v = *(const float4*)(src + node * EMB + j);
    float4 o = *(const float4*)(out + (long long)b * EMB + j);
    o.x += 0.25f * v.x; o.y += 0.25f * v.y; o.z += 0.25f * v.z; o.w += 0.25f * v.w;
    *(float4*)(out + (long long)b * EMB + j) = o;
}

// ---------------------------------------------------------------------------
// COO SpMM scatter: y[row,:] += val * x[col,:]
// 32 lanes per edge, float4 per lane, 4 atomicAdds.
// If x == nullptr, source is the virtual concat(user_emb, item_emb).
// ---------------------------------------------------------------------------
__global__ void spmm_scatter(const float* __restrict__ vals,
                             const int*   __restrict__ rows,
                             const int*   __restrict__ cols,
                             const float* __restrict__ x,        // may be null
                             const float* __restrict__ user_emb,
                             const float* __restrict__ item_emb,
                             float* __restrict__ y)
{
    long long gid = (long long)blockIdx.x * blockDim.x + threadIdx.x;
    long long e = gid >> 5;
    int j = (int)(gid & 31) * 4;
    if (e >= NNZ) return;
    float v = vals[e];
    int   r = rows[e];
    int   c = cols[e];
    const float* src;
    if (x) {
        src = x + (long long)c * EMB;
    } else {
        src = (c < USER_COUNT) ? user_emb + (long long)c * EMB
                               : item_emb + (long long)(c - USER_COUNT) * EMB;
    }
    float4 xv = *(const float4*)(src + j);
    float* dst = y + (long long)r * EMB + j;
    atomicAdd(dst + 0, v * xv.x);
    atomicAdd(dst + 1, v * xv.y);
    atomicAdd(dst + 2, v * xv.z);
    atomicAdd(dst + 3, v * xv.w);
}

extern "C" void kernel_launch(void* const* d_in, const int* in_sizes, int n_in,
                              void* d_out, int out_size, void* d_ws, size_t ws_size,
                              hipStream_t stream) {
    const float* user_emb = (const float*)d_in[0];
    const float* item_emb = (const float*)d_in[1];
    const float* adj_vals = (const float*)d_in[2];
    const int*   adj_rows = (const int*)d_in[3];
    const int*   adj_cols = (const int*)d_in[4];
    const int*   users    = (const int*)d_in[5];
    const int*   items    = (const int*)d_in[6];
    float* out = (float*)d_out;

    const size_t node_elems = (size_t)N_NODES * EMB;     // 19.2M floats
    float* buf0 = (float*)d_ws;
    float* buf1 = buf0 + node_elems;

    // Layer 0 contribution (init d_out — it is poisoned before each launch)
    {
        int total = 2 * BATCH * 32;
        gather_init<<<(total + 255) / 256, 256, 0, stream>>>(
            user_emb, item_emb, users, items, out);
    }

    const float* src = nullptr;   // virtual concat for layer 1
    float* dst = buf0;
    for (int layer = 0; layer < N_LAYERS; ++layer) {
        hipMemsetAsync(dst, 0, node_elems * sizeof(float), stream);
        {
            long long total = (long long)NNZ * 32;       // 51.2M threads
            int blocks = (int)((total + 255) / 256);
            spmm_scatter<<<blocks, 256, 0, stream>>>(
                adj_vals, adj_rows, adj_cols, src, user_emb, item_emb, dst);
        }
        {
            int total = 2 * BATCH * 32;
            gather_acc<<<(total + 255) / 256, 256, 0, stream>>>(
                dst, users, items, out);
        }
        src = dst;
        dst = (dst == buf0) ? buf1 : buf0;
    }
}

// Round 2
// 819.445 us; speedup vs baseline: 9.9453x; 9.9453x over previous
//
#include <hip/hip_runtime.h>
#include <hip/hip_bf16.h>

// Problem constants (match reference)
#define USER_COUNT 100000
#define ITEM_COUNT 50000
#define N_NODES    (USER_COUNT + ITEM_COUNT)   // 150000
#define EMB        128
#define N_LAYERS   3
#define NNZ        1600000
#define BATCH      4096

#define SCAN_BLOCK 256
#define N_SBLOCKS  ((N_NODES + SCAN_BLOCK - 1) / SCAN_BLOCK)   // 586

// ---------------------------------------------------------------------------
// Output gather: out = 0.25 * concat(user_emb,item_emb)[sel rows]  (layer 0)
// ---------------------------------------------------------------------------
__global__ void gather_init(const float* __restrict__ user_emb,
                            const float* __restrict__ item_emb,
                            const int*   __restrict__ users,
                            const int*   __restrict__ items,
                            float* __restrict__ out)
{
    int gid = blockIdx.x * blockDim.x + threadIdx.x;   // [0, 2*BATCH*32)
    int b = gid >> 5;
    int j = (gid & 31) * 4;
    if (b >= 2 * BATCH) return;
    const float* src;
    if (b < BATCH) src = user_emb + (size_t)users[b] * EMB;
    else           src = item_emb + (size_t)items[b - BATCH] * EMB;
    float4 v = *(const float4*)(src + j);
    float4 o = { 0.25f * v.x, 0.25f * v.y, 0.25f * v.z, 0.25f * v.w };
    *(float4*)(out + (size_t)b * EMB + j) = o;
}

// out += 0.25 * src[sel rows]
__global__ void gather_acc(const float* __restrict__ src,
                           const int*   __restrict__ users,
                           const int*   __restrict__ items,
                           float* __restrict__ out)
{
    int gid = blockIdx.x * blockDim.x + threadIdx.x;
    int b = gid >> 5;
    int j = (gid & 31) * 4;
    if (b >= 2 * BATCH) return;
    size_t node;
    if (b < BATCH) node = (size_t)users[b];
    else           node = (size_t)USER_COUNT + items[b - BATCH];
    float4 v = *(const float4*)(src + node * EMB + j);
    float4 o = *(const float4*)(out + (size_t)b * EMB + j);
    o.x += 0.25f * v.x; o.y += 0.25f * v.y; o.z += 0.25f * v.z; o.w += 0.25f * v.w;
    *(float4*)(out + (size_t)b * EMB + j) = o;
}

// ---------------------------------------------------------------------------
// CSR build: histogram -> 3-kernel exclusive scan -> fill
// ---------------------------------------------------------------------------
__global__ void hist_rows(const int* __restrict__ rows, int* __restrict__ counts)
{
    int e = blockIdx.x * blockDim.x + threadIdx.x;
    if (e < NNZ) atomicAdd(&counts[rows[e]], 1);
}

// S1: per-block sums of counts (256 elems per block)
__global__ void scan_s1(const int* __restrict__ counts, int* __restrict__ blocksum)
{
    int i = blockIdx.x * SCAN_BLOCK + threadIdx.x;
    int v = (i < N_NODES) ? counts[i] : 0;
    #pragma unroll
    for (int off = 32; off >= 1; off >>= 1) v += __shfl_down(v, off, 64);
    __shared__ int ws[SCAN_BLOCK / 64];
    int lane = threadIdx.x & 63, wid = threadIdx.x >> 6;
    if (lane == 0) ws[wid] = v;
    __syncthreads();
    if (threadIdx.x == 0) {
        int s = 0;
        #pragma unroll
        for (int w = 0; w < SCAN_BLOCK / 64; ++w) s += ws[w];
        blocksum[blockIdx.x] = s;
    }
}

// S2: single-block exclusive scan of the 586 block sums (1024 threads)
__global__ void scan_s2(int* __restrict__ blocksum)
{
    __shared__ int sm[1024];
    int t = threadIdx.x;
    int v = (t < N_SBLOCKS) ? blocksum[t] : 0;
    sm[t] = v;
    __syncthreads();
    #pragma unroll
    for (int off = 1; off < 1024; off <<= 1) {
        int tv = (t >= off) ? sm[t - off] : 0;
        __syncthreads();
        sm[t] += tv;
        __syncthreads();
    }
    if (t < N_SBLOCKS) blocksum[t] = sm[t] - v;   // exclusive
}

// S3: per-block exclusive scan + block offset -> row_start and fill
__global__ void scan_s3(const int* __restrict__ counts,
                        const int* __restrict__ blocksum,
                        int* __restrict__ row_start,
                        int* __restrict__ fill)
{
    __shared__ int sm[SCAN_BLOCK];
    int t = threadIdx.x;
    int i = blockIdx.x * SCAN_BLOCK + t;
    int v = (i < N_NODES) ? counts[i] : 0;
    sm[t] = v;
    __syncthreads();
    #pragma unroll
    for (int off = 1; off < SCAN_BLOCK; off <<= 1) {
        int tv = (t >= off) ? sm[t - off] : 0;
        __syncthreads();
        sm[t] += tv;
        __syncthreads();
    }
    if (i < N_NODES) {
        int excl = blocksum[blockIdx.x] + sm[t] - v;
        row_start[i] = excl;
        fill[i] = excl;
        if (i == N_NODES - 1) row_start[N_NODES] = excl + v;
    }
}

// Fill: scatter (col,val) pairs into CSR slots
__global__ void csr_fill(const int* __restrict__ rows,
                         const int* __restrict__ cols,
                         const float* __restrict__ vals,
                         int* __restrict__ fill,
                         int2* __restrict__ csr)
{
    int e = blockIdx.x * blockDim.x + threadIdx.x;
    if (e >= NNZ) return;
    int pos = atomicAdd(&fill[rows[e]], 1);
    csr[pos] = make_int2(cols[e], __float_as_int(vals[e]));
}

// ---------------------------------------------------------------------------
// CSR SpMM gather: one wave per row; lane holds float2 (64*2 = 128 cols).
// If x == nullptr, source rows come from the virtual concat(user_emb,item_emb).
// ---------------------------------------------------------------------------
__global__ void spmm_csr(const int*  __restrict__ row_start,
                         const int2* __restrict__ csr,
                         const float* __restrict__ x,
                         const float* __restrict__ user_emb,
                         const float* __restrict__ item_emb,
                         float* __restrict__ y)
{
    int wid  = threadIdx.x >> 6;            // wave in block: 0..3
    int lane = threadIdx.x & 63;
    int r = blockIdx.x * 4 + wid;
    if (r >= N_NODES) return;
    int s = row_start[r];
    int e = row_start[r + 1];
    int j = lane * 2;
    float2 acc = { 0.f, 0.f };
    for (int k = s; k < e; ++k) {
        int2 p = csr[k];                    // broadcast load (same addr all lanes)
        int   c = p.x;
        float v = __int_as_float(p.y);
        const float* src;
        if (x) src = x + (size_t)c * EMB;
        else   src = (c < USER_COUNT) ? user_emb + (size_t)c * EMB
                                      : item_emb + (size_t)(c - USER_COUNT) * EMB;
        float2 xv = *(const float2*)(src + j);
        acc.x += v * xv.x;
        acc.y += v * xv.y;
    }
    *(float2*)(y + (size_t)r * EMB + j) = acc;
}

extern "C" void kernel_launch(void* const* d_in, const int* in_sizes, int n_in,
                              void* d_out, int out_size, void* d_ws, size_t ws_size,
                              hipStream_t stream) {
    const float* user_emb = (const float*)d_in[0];
    const float* item_emb = (const float*)d_in[1];
    const float* adj_vals = (const float*)d_in[2];
    const int*   adj_rows = (const int*)d_in[3];
    const int*   adj_cols = (const int*)d_in[4];
    const int*   users    = (const int*)d_in[5];
    const int*   items    = (const int*)d_in[6];
    float* out = (float*)d_out;

    // Workspace layout (all 16B-aligned):
    //   buf0, buf1 : 19,200,000 floats each (76.8 MB each)
    //   counts     : N_NODES ints
    //   row_start  : N_NODES+1 ints
    //   fill       : N_NODES ints
    //   blocksum   : 1024 ints
    //   csr        : NNZ int2 (12.8 MB)
    const size_t node_elems = (size_t)N_NODES * EMB;
    char* p = (char*)d_ws;
    float* buf0 = (float*)p;                 p += node_elems * sizeof(float);
    float* buf1 = (float*)p;                 p += node_elems * sizeof(float);
    int* counts    = (int*)p;                p += ((N_NODES + 3) & ~3) * sizeof(int);
    int* row_start = (int*)p;                p += ((N_NODES + 1 + 3) & ~3) * sizeof(int);
    int* fill      = (int*)p;                p += ((N_NODES + 3) & ~3) * sizeof(int);
    int* blocksum  = (int*)p;                p += 1024 * sizeof(int);
    int2* csr      = (int2*)p;

    // ---- CSR build ----
    hipMemsetAsync(counts, 0, (size_t)N_NODES * sizeof(int), stream);
    hist_rows<<<(NNZ + 255) / 256, 256, 0, stream>>>(adj_rows, counts);
    scan_s1<<<N_SBLOCKS, SCAN_BLOCK, 0, stream>>>(counts, blocksum);
    scan_s2<<<1, 1024, 0, stream>>>(blocksum);
    scan_s3<<<N_SBLOCKS, SCAN_BLOCK, 0, stream>>>(counts, blocksum, row_start, fill);
    csr_fill<<<(NNZ + 255) / 256, 256, 0, stream>>>(adj_rows, adj_cols, adj_vals, fill, csr);

    // ---- Layer 0 contribution ----
    {
        int total = 2 * BATCH * 32;
        gather_init<<<(total + 255) / 256, 256, 0, stream>>>(
            user_emb, item_emb, users, items, out);
    }

    // ---- 3 SpMM layers, gather-accumulate selected rows after each ----
    const float* src = nullptr;   // virtual concat for layer 1
    float* dst = buf0;
    for (int layer = 0; layer < N_LAYERS; ++layer) {
        spmm_csr<<<(N_NODES + 3) / 4, 256, 0, stream>>>(
            row_start, csr, src, user_emb, item_emb, dst);
        int total = 2 * BATCH * 32;
        gather_acc<<<(total + 255) / 256, 256, 0, stream>>>(
            dst, users, items, out);
        src = dst;
        dst = (dst == buf0) ? buf1 : buf0;
    }
}

// Round 3
// 678.582 us; speedup vs baseline: 12.0098x; 1.2076x over previous
//
#include <hip/hip_runtime.h>
#include <hip/hip_bf16.h>

// Problem constants (match reference)
#define USER_COUNT 100000
#define ITEM_COUNT 50000
#define N_NODES    (USER_COUNT + ITEM_COUNT)   // 150000
#define EMB        128
#define N_LAYERS   3
#define NNZ        1600000
#define BATCH      4096

#define SCAN_BLOCK 256
#define N_SBLOCKS  ((N_NODES + SCAN_BLOCK - 1) / SCAN_BLOCK)   // 586

// ---------------------------------------------------------------------------
// Output gather: out = 0.25 * concat(user_emb,item_emb)[sel rows]  (layer 0)
// ---------------------------------------------------------------------------
__global__ void gather_init(const float* __restrict__ user_emb,
                            const float* __restrict__ item_emb,
                            const int*   __restrict__ users,
                            const int*   __restrict__ items,
                            float* __restrict__ out)
{
    int gid = blockIdx.x * blockDim.x + threadIdx.x;   // [0, 2*BATCH*32)
    int b = gid >> 5;
    int j = (gid & 31) * 4;
    if (b >= 2 * BATCH) return;
    const float* src;
    if (b < BATCH) src = user_emb + (size_t)users[b] * EMB;
    else           src = item_emb + (size_t)items[b - BATCH] * EMB;
    float4 v = *(const float4*)(src + j);
    float4 o = { 0.25f * v.x, 0.25f * v.y, 0.25f * v.z, 0.25f * v.w };
    *(float4*)(out + (size_t)b * EMB + j) = o;
}

// out += 0.25 * src[sel rows]
__global__ void gather_acc(const float* __restrict__ src,
                           const int*   __restrict__ users,
                           const int*   __restrict__ items,
                           float* __restrict__ out)
{
    int gid = blockIdx.x * blockDim.x + threadIdx.x;
    int b = gid >> 5;
    int j = (gid & 31) * 4;
    if (b >= 2 * BATCH) return;
    size_t node;
    if (b < BATCH) node = (size_t)users[b];
    else           node = (size_t)USER_COUNT + items[b - BATCH];
    float4 v = *(const float4*)(src + node * EMB + j);
    float4 o = *(const float4*)(out + (size_t)b * EMB + j);
    o.x += 0.25f * v.x; o.y += 0.25f * v.y; o.z += 0.25f * v.z; o.w += 0.25f * v.w;
    *(float4*)(out + (size_t)b * EMB + j) = o;
}

// ---------------------------------------------------------------------------
// CSR build: histogram -> 3-kernel exclusive scan -> fill
// ---------------------------------------------------------------------------
__global__ void hist_rows(const int* __restrict__ rows, int* __restrict__ counts)
{
    int e = blockIdx.x * blockDim.x + threadIdx.x;
    if (e < NNZ) atomicAdd(&counts[rows[e]], 1);
}

__global__ void scan_s1(const int* __restrict__ counts, int* __restrict__ blocksum)
{
    int i = blockIdx.x * SCAN_BLOCK + threadIdx.x;
    int v = (i < N_NODES) ? counts[i] : 0;
    #pragma unroll
    for (int off = 32; off >= 1; off >>= 1) v += __shfl_down(v, off, 64);
    __shared__ int ws[SCAN_BLOCK / 64];
    int lane = threadIdx.x & 63, wid = threadIdx.x >> 6;
    if (lane == 0) ws[wid] = v;
    __syncthreads();
    if (threadIdx.x == 0) {
        int s = 0;
        #pragma unroll
        for (int w = 0; w < SCAN_BLOCK / 64; ++w) s += ws[w];
        blocksum[blockIdx.x] = s;
    }
}

__global__ void scan_s2(int* __restrict__ blocksum)
{
    __shared__ int sm[1024];
    int t = threadIdx.x;
    int v = (t < N_SBLOCKS) ? blocksum[t] : 0;
    sm[t] = v;
    __syncthreads();
    #pragma unroll
    for (int off = 1; off < 1024; off <<= 1) {
        int tv = (t >= off) ? sm[t - off] : 0;
        __syncthreads();
        sm[t] += tv;
        __syncthreads();
    }
    if (t < N_SBLOCKS) blocksum[t] = sm[t] - v;   // exclusive
}

__global__ void scan_s3(const int* __restrict__ counts,
                        const int* __restrict__ blocksum,
                        int* __restrict__ row_start,
                        int* __restrict__ fill)
{
    __shared__ int sm[SCAN_BLOCK];
    int t = threadIdx.x;
    int i = blockIdx.x * SCAN_BLOCK + t;
    int v = (i < N_NODES) ? counts[i] : 0;
    sm[t] = v;
    __syncthreads();
    #pragma unroll
    for (int off = 1; off < SCAN_BLOCK; off <<= 1) {
        int tv = (t >= off) ? sm[t - off] : 0;
        __syncthreads();
        sm[t] += tv;
        __syncthreads();
    }
    if (i < N_NODES) {
        int excl = blocksum[blockIdx.x] + sm[t] - v;
        row_start[i] = excl;
        fill[i] = excl;
        if (i == N_NODES - 1) row_start[N_NODES] = excl + v;
    }
}

__global__ void csr_fill(const int* __restrict__ rows,
                         const int* __restrict__ cols,
                         const float* __restrict__ vals,
                         int* __restrict__ fill,
                         int2* __restrict__ csr)
{
    int e = blockIdx.x * blockDim.x + threadIdx.x;
    if (e >= NNZ) return;
    int pos = atomicAdd(&fill[rows[e]], 1);
    csr[pos] = make_int2(cols[e], __float_as_int(vals[e]));
}

// ---------------------------------------------------------------------------
// CSR SpMM gather, 4x-unrolled with clamped-index predication.
// One wave per row; lane holds float2 (64*2 = 128 cols).
// If x == nullptr, source rows come from the virtual concat(user_emb,item_emb).
// ---------------------------------------------------------------------------
__global__ void spmm_csr(const int*  __restrict__ row_start,
                         const int2* __restrict__ csr,
                         const float* __restrict__ x,
                         const float* __restrict__ user_emb,
                         const float* __restrict__ item_emb,
                         float* __restrict__ y)
{
    int wid  = threadIdx.x >> 6;            // wave in block: 0..3
    int lane = threadIdx.x & 63;
    int r = blockIdx.x * 4 + wid;
    if (r >= N_NODES) return;
    int s = row_start[r];
    int e = row_start[r + 1];
    int j = lane * 2;
    float2 acc = { 0.f, 0.f };

    for (int k = s; k < e; k += 4) {
        int k1 = (k + 1 < e) ? k + 1 : e - 1;
        int k2 = (k + 2 < e) ? k + 2 : e - 1;
        int k3 = (k + 3 < e) ? k + 3 : e - 1;
        int2 p0 = csr[k];
        int2 p1 = csr[k1];
        int2 p2 = csr[k2];
        int2 p3 = csr[k3];
        float v0 = __int_as_float(p0.y);
        float v1 = (k + 1 < e) ? __int_as_float(p1.y) : 0.f;
        float v2 = (k + 2 < e) ? __int_as_float(p2.y) : 0.f;
        float v3 = (k + 3 < e) ? __int_as_float(p3.y) : 0.f;
        const float *s0, *s1, *s2, *s3;
        if (x) {
            s0 = x + (size_t)p0.x * EMB;
            s1 = x + (size_t)p1.x * EMB;
            s2 = x + (size_t)p2.x * EMB;
            s3 = x + (size_t)p3.x * EMB;
        } else {
            s0 = (p0.x < USER_COUNT) ? user_emb + (size_t)p0.x * EMB
                                     : item_emb + (size_t)(p0.x - USER_COUNT) * EMB;
            s1 = (p1.x < USER_COUNT) ? user_emb + (size_t)p1.x * EMB
                                     : item_emb + (size_t)(p1.x - USER_COUNT) * EMB;
            s2 = (p2.x < USER_COUNT) ? user_emb + (size_t)p2.x * EMB
                                     : item_emb + (size_t)(p2.x - USER_COUNT) * EMB;
            s3 = (p3.x < USER_COUNT) ? user_emb + (size_t)p3.x * EMB
                                     : item_emb + (size_t)(p3.x - USER_COUNT) * EMB;
        }
        float2 x0 = *(const float2*)(s0 + j);
        float2 x1 = *(const float2*)(s1 + j);
        float2 x2 = *(const float2*)(s2 + j);
        float2 x3 = *(const float2*)(s3 + j);
        acc.x += v0 * x0.x + v1 * x1.x + v2 * x2.x + v3 * x3.x;
        acc.y += v0 * x0.y + v1 * x1.y + v2 * x2.y + v3 * x3.y;
    }
    *(float2*)(y + (size_t)r * EMB + j) = acc;
}

extern "C" void kernel_launch(void* const* d_in, const int* in_sizes, int n_in,
                              void* d_out, int out_size, void* d_ws, size_t ws_size,
                              hipStream_t stream) {
    const float* user_emb = (const float*)d_in[0];
    const float* item_emb = (const float*)d_in[1];
    const float* adj_vals = (const float*)d_in[2];
    const int*   adj_rows = (const int*)d_in[3];
    const int*   adj_cols = (const int*)d_in[4];
    const int*   users    = (const int*)d_in[5];
    const int*   items    = (const int*)d_in[6];
    float* out = (float*)d_out;

    const size_t node_elems = (size_t)N_NODES * EMB;
    char* p = (char*)d_ws;
    float* buf0 = (float*)p;                 p += node_elems * sizeof(float);
    float* buf1 = (float*)p;                 p += node_elems * sizeof(float);
    int* counts    = (int*)p;                p += ((N_NODES + 3) & ~3) * sizeof(int);
    int* row_start = (int*)p;                p += ((N_NODES + 1 + 3) & ~3) * sizeof(int);
    int* fill      = (int*)p;                p += ((N_NODES + 3) & ~3) * sizeof(int);
    int* blocksum  = (int*)p;                p += 1024 * sizeof(int);
    int2* csr      = (int2*)p;

    // ---- CSR build ----
    hipMemsetAsync(counts, 0, (size_t)N_NODES * sizeof(int), stream);
    hist_rows<<<(NNZ + 255) / 256, 256, 0, stream>>>(adj_rows, counts);
    scan_s1<<<N_SBLOCKS, SCAN_BLOCK, 0, stream>>>(counts, blocksum);
    scan_s2<<<1, 1024, 0, stream>>>(blocksum);
    scan_s3<<<N_SBLOCKS, SCAN_BLOCK, 0, stream>>>(counts, blocksum, row_start, fill);
    csr_fill<<<(NNZ + 255) / 256, 256, 0, stream>>>(adj_rows, adj_cols, adj_vals, fill, csr);

    // ---- Layer 0 contribution ----
    {
        int total = 2 * BATCH * 32;
        gather_init<<<(total + 255) / 256, 256, 0, stream>>>(
            user_emb, item_emb, users, items, out);
    }

    // ---- 3 SpMM layers, gather-accumulate selected rows after each ----
    const float* src = nullptr;   // virtual concat for layer 1
    float* dst = buf0;
    for (int layer = 0; layer < N_LAYERS; ++layer) {
        spmm_csr<<<(N_NODES + 3) / 4, 256, 0, stream>>>(
            row_start, csr, src, user_emb, item_emb, dst);
        int total = 2 * BATCH * 32;
        gather_acc<<<(total + 255) / 256, 256, 0, stream>>>(
            dst, users, items, out);
        src = dst;
        dst = (dst == buf0) ? buf1 : buf0;
    }
}

// Round 5
// 540.395 us; speedup vs baseline: 15.0808x; 1.2557x over previous
//
#include <hip/hip_runtime.h>
#include <hip/hip_bf16.h>

// Problem constants (match reference)
#define USER_COUNT 100000
#define ITEM_COUNT 50000
#define N_NODES    (USER_COUNT + ITEM_COUNT)   // 150000
#define EMB        128
#define N_LAYERS   3
#define NNZ        1600000
#define BATCH      4096

#define SCAN_BLOCK 256
#define N_SBLOCKS  ((N_NODES + SCAN_BLOCK - 1) / SCAN_BLOCK)   // 586

// ---------------------------------------------------------------------------
// Output gather: out = 0.25 * concat(user_emb,item_emb)[sel rows]  (layer 0)
// ---------------------------------------------------------------------------
__global__ void gather_init(const float* __restrict__ user_emb,
                            const float* __restrict__ item_emb,
                            const int*   __restrict__ users,
                            const int*   __restrict__ items,
                            float* __restrict__ out)
{
    int gid = blockIdx.x * blockDim.x + threadIdx.x;   // [0, 2*BATCH*32)
    int b = gid >> 5;
    int j = (gid & 31) * 4;
    if (b >= 2 * BATCH) return;
    const float* src;
    if (b < BATCH) src = user_emb + (size_t)users[b] * EMB;
    else           src = item_emb + (size_t)items[b - BATCH] * EMB;
    float4 v = *(const float4*)(src + j);
    float4 o = { 0.25f * v.x, 0.25f * v.y, 0.25f * v.z, 0.25f * v.w };
    *(float4*)(out + (size_t)b * EMB + j) = o;
}

// out += 0.25 * src[sel rows]
__global__ void gather_acc(const float* __restrict__ src,
                           const int*   __restrict__ users,
                           const int*   __restrict__ items,
                           float* __restrict__ out)
{
    int gid = blockIdx.x * blockDim.x + threadIdx.x;
    int b = gid >> 5;
    int j = (gid & 31) * 4;
    if (b >= 2 * BATCH) return;
    size_t node;
    if (b < BATCH) node = (size_t)users[b];
    else           node = (size_t)USER_COUNT + items[b - BATCH];
    float4 v = *(const float4*)(src + node * EMB + j);
    float4 o = *(const float4*)(out + (size_t)b * EMB + j);
    o.x += 0.25f * v.x; o.y += 0.25f * v.y; o.z += 0.25f * v.z; o.w += 0.25f * v.w;
    *(float4*)(out + (size_t)b * EMB + j) = o;
}

// ---------------------------------------------------------------------------
// CSR build: histogram -> 3-kernel exclusive scan -> fill
// ---------------------------------------------------------------------------
__global__ void hist_rows(const int* __restrict__ rows, int* __restrict__ counts)
{
    int e = blockIdx.x * blockDim.x + threadIdx.x;
    if (e < NNZ) atomicAdd(&counts[rows[e]], 1);
}

__global__ void scan_s1(const int* __restrict__ counts, int* __restrict__ blocksum)
{
    int i = blockIdx.x * SCAN_BLOCK + threadIdx.x;
    int v = (i < N_NODES) ? counts[i] : 0;
    #pragma unroll
    for (int off = 32; off >= 1; off >>= 1) v += __shfl_down(v, off, 64);
    __shared__ int ws[SCAN_BLOCK / 64];
    int lane = threadIdx.x & 63, wid = threadIdx.x >> 6;
    if (lane == 0) ws[wid] = v;
    __syncthreads();
    if (threadIdx.x == 0) {
        int s = 0;
        #pragma unroll
        for (int w = 0; w < SCAN_BLOCK / 64; ++w) s += ws[w];
        blocksum[blockIdx.x] = s;
    }
}

__global__ void scan_s2(int* __restrict__ blocksum)
{
    __shared__ int sm[1024];
    int t = threadIdx.x;
    int v = (t < N_SBLOCKS) ? blocksum[t] : 0;
    sm[t] = v;
    __syncthreads();
    #pragma unroll
    for (int off = 1; off < 1024; off <<= 1) {
        int tv = (t >= off) ? sm[t - off] : 0;
        __syncthreads();
        sm[t] += tv;
        __syncthreads();
    }
    if (t < N_SBLOCKS) blocksum[t] = sm[t] - v;   // exclusive
}

__global__ void scan_s3(const int* __restrict__ counts,
                        const int* __restrict__ blocksum,
                        int* __restrict__ row_start,
                        int* __restrict__ fill)
{
    __shared__ int sm[SCAN_BLOCK];
    int t = threadIdx.x;
    int i = blockIdx.x * SCAN_BLOCK + t;
    int v = (i < N_NODES) ? counts[i] : 0;
    sm[t] = v;
    __syncthreads();
    #pragma unroll
    for (int off = 1; off < SCAN_BLOCK; off <<= 1) {
        int tv = (t >= off) ? sm[t - off] : 0;
        __syncthreads();
        sm[t] += tv;
        __syncthreads();
    }
    if (i < N_NODES) {
        int excl = blocksum[blockIdx.x] + sm[t] - v;
        row_start[i] = excl;
        fill[i] = excl;
        if (i == N_NODES - 1) row_start[N_NODES] = excl + v;
    }
}

__global__ void csr_fill(const int* __restrict__ rows,
                         const int* __restrict__ cols,
                         const float* __restrict__ vals,
                         int* __restrict__ fill,
                         int2* __restrict__ csr)
{
    int e = blockIdx.x * blockDim.x + threadIdx.x;
    if (e >= NNZ) return;
    int pos = atomicAdd(&fill[rows[e]], 1);
    csr[pos] = make_int2(cols[e], __float_as_int(vals[e]));
}

// ---------------------------------------------------------------------------
// Full SpMM, dense source x. Half-wave (32 lanes x float4 = 128 features)
// per row; 4-edge unroll with clamped-index predication.
// Block 256 = 8 half-waves = 8 rows.
// ---------------------------------------------------------------------------
__global__ void spmm_x(const int*  __restrict__ row_start,
                       const int2* __restrict__ csr,
                       const float* __restrict__ x,
                       float* __restrict__ y)
{
    int half = threadIdx.x >> 5;            // 0..7
    int r = blockIdx.x * 8 + half;
    if (r >= N_NODES) return;
    int j = (threadIdx.x & 31) * 4;
    int s = row_start[r];
    int e = row_start[r + 1];
    float4 acc = { 0.f, 0.f, 0.f, 0.f };
    for (int k = s; k < e; k += 4) {
        int i1 = (k + 1 < e) ? k + 1 : e - 1;
        int i2 = (k + 2 < e) ? k + 2 : e - 1;
        int i3 = (k + 3 < e) ? k + 3 : e - 1;
        int2 p0 = csr[k];
        int2 p1 = csr[i1];
        int2 p2 = csr[i2];
        int2 p3 = csr[i3];
        float v0 = __int_as_float(p0.y);
        float v1 = (k + 1 < e) ? __int_as_float(p1.y) : 0.f;
        float v2 = (k + 2 < e) ? __int_as_float(p2.y) : 0.f;
        float v3 = (k + 3 < e) ? __int_as_float(p3.y) : 0.f;
        float4 x0 = *(const float4*)(x + (size_t)p0.x * EMB + j);
        float4 x1 = *(const float4*)(x + (size_t)p1.x * EMB + j);
        float4 x2 = *(const float4*)(x + (size_t)p2.x * EMB + j);
        float4 x3 = *(const float4*)(x + (size_t)p3.x * EMB + j);
        acc.x += v0 * x0.x + v1 * x1.x + v2 * x2.x + v3 * x3.x;
        acc.y += v0 * x0.y + v1 * x1.y + v2 * x2.y + v3 * x3.y;
        acc.z += v0 * x0.z + v1 * x1.z + v2 * x2.z + v3 * x3.z;
        acc.w += v0 * x0.w + v1 * x1.w + v2 * x2.w + v3 * x3.w;
    }
    *(float4*)(y + (size_t)r * EMB + j) = acc;
}

// Full SpMM, virtual concat(user_emb,item_emb) source (layer 1).
__global__ void spmm_concat(const int*  __restrict__ row_start,
                            const int2* __restrict__ csr,
                            const float* __restrict__ user_emb,
                            const float* __restrict__ item_emb,
                            float* __restrict__ y)
{
    int half = threadIdx.x >> 5;
    int r = blockIdx.x * 8 + half;
    if (r >= N_NODES) return;
    int j = (threadIdx.x & 31) * 4;
    int s = row_start[r];
    int e = row_start[r + 1];
    float4 acc = { 0.f, 0.f, 0.f, 0.f };
    for (int k = s; k < e; k += 4) {
        int i1 = (k + 1 < e) ? k + 1 : e - 1;
        int i2 = (k + 2 < e) ? k + 2 : e - 1;
        int i3 = (k + 3 < e) ? k + 3 : e - 1;
        int2 p0 = csr[k];
        int2 p1 = csr[i1];
        int2 p2 = csr[i2];
        int2 p3 = csr[i3];
        float v0 = __int_as_float(p0.y);
        float v1 = (k + 1 < e) ? __int_as_float(p1.y) : 0.f;
        float v2 = (k + 2 < e) ? __int_as_float(p2.y) : 0.f;
        float v3 = (k + 3 < e) ? __int_as_float(p3.y) : 0.f;
        const float* s0 = (p0.x < USER_COUNT) ? user_emb + (size_t)p0.x * EMB
                                              : item_emb + (size_t)(p0.x - USER_COUNT) * EMB;
        const float* s1 = (p1.x < USER_COUNT) ? user_emb + (size_t)p1.x * EMB
                                              : item_emb + (size_t)(p1.x - USER_COUNT) * EMB;
        const float* s2 = (p2.x < USER_COUNT) ? user_emb + (size_t)p2.x * EMB
                                              : item_emb + (size_t)(p2.x - USER_COUNT) * EMB;
        const float* s3 = (p3.x < USER_COUNT) ? user_emb + (size_t)p3.x * EMB
                                              : item_emb + (size_t)(p3.x - USER_COUNT) * EMB;
        float4 x0 = *(const float4*)(s0 + j);
        float4 x1 = *(const float4*)(s1 + j);
        float4 x2 = *(const float4*)(s2 + j);
        float4 x3 = *(const float4*)(s3 + j);
        acc.x += v0 * x0.x + v1 * x1.x + v2 * x2.x + v3 * x3.x;
        acc.y += v0 * x0.y + v1 * x1.y + v2 * x2.y + v3 * x3.y;
        acc.z += v0 * x0.z + v1 * x1.z + v2 * x2.z + v3 * x3.z;
        acc.w += v0 * x0.w + v1 * x1.w + v2 * x2.w + v3 * x3.w;
    }
    *(float4*)(y + (size_t)r * EMB + j) = acc;
}

// Selective SpMM for the final layer: half-wave per OUTPUT row (8192 total);
// out[b] += 0.25 * (A x)[node(b)].
__global__ void spmm_sel(const int*  __restrict__ row_start,
                         const int2* __restrict__ csr,
                         const float* __restrict__ x,
                         const int*   __restrict__ users,
                         const int*   __restrict__ items,
                         float* __restrict__ out)
{
    int half = threadIdx.x >> 5;
    int b = blockIdx.x * 8 + half;
    if (b >= 2 * BATCH) return;
    int node = (b < BATCH) ? users[b] : USER_COUNT + items[b - BATCH];
    int j = (threadIdx.x & 31) * 4;
    int s = row_start[node];
    int e = row_start[node + 1];
    float4 acc = { 0.f, 0.f, 0.f, 0.f };
    for (int k = s; k < e; k += 4) {
        int i1 = (k + 1 < e) ? k + 1 : e - 1;
        int i2 = (k + 2 < e) ? k + 2 : e - 1;
        int i3 = (k + 3 < e) ? k + 3 : e - 1;
        int2 p0 = csr[k];
        int2 p1 = csr[i1];
        int2 p2 = csr[i2];
        int2 p3 = csr[i3];
        float v0 = __int_as_float(p0.y);
        float v1 = (k + 1 < e) ? __int_as_float(p1.y) : 0.f;
        float v2 = (k + 2 < e) ? __int_as_float(p2.y) : 0.f;
        float v3 = (k + 3 < e) ? __int_as_float(p3.y) : 0.f;
        float4 x0 = *(const float4*)(x + (size_t)p0.x * EMB + j);
        float4 x1 = *(const float4*)(x + (size_t)p1.x * EMB + j);
        float4 x2 = *(const float4*)(x + (size_t)p2.x * EMB + j);
        float4 x3 = *(const float4*)(x + (size_t)p3.x * EMB + j);
        acc.x += v0 * x0.x + v1 * x1.x + v2 * x2.x + v3 * x3.x;
        acc.y += v0 * x0.y + v1 * x1.y + v2 * x2.y + v3 * x3.y;
        acc.z += v0 * x0.z + v1 * x1.z + v2 * x2.z + v3 * x3.z;
        acc.w += v0 * x0.w + v1 * x1.w + v2 * x2.w + v3 * x3.w;
    }
    float4 o = *(const float4*)(out + (size_t)b * EMB + j);
    o.x += 0.25f * acc.x; o.y += 0.25f * acc.y;
    o.z += 0.25f * acc.z; o.w += 0.25f * acc.w;
    *(float4*)(out + (size_t)b * EMB + j) = o;
}

extern "C" void kernel_launch(void* const* d_in, const int* in_sizes, int n_in,
                              void* d_out, int out_size, void* d_ws, size_t ws_size,
                              hipStream_t stream) {
    const float* user_emb = (const float*)d_in[0];
    const float* item_emb = (const float*)d_in[1];
    const float* adj_vals = (const float*)d_in[2];
    const int*   adj_rows = (const int*)d_in[3];
    const int*   adj_cols = (const int*)d_in[4];
    const int*   users    = (const int*)d_in[5];
    const int*   items    = (const int*)d_in[6];
    float* out = (float*)d_out;

    const size_t node_elems = (size_t)N_NODES * EMB;
    char* p = (char*)d_ws;
    float* buf0 = (float*)p;                 p += node_elems * sizeof(float);
    float* buf1 = (float*)p;                 p += node_elems * sizeof(float);
    int* counts    = (int*)p;                p += ((N_NODES + 3) & ~3) * sizeof(int);
    int* row_start = (int*)p;                p += ((N_NODES + 1 + 3) & ~3) * sizeof(int);
    int* fill      = (int*)p;                p += ((N_NODES + 3) & ~3) * sizeof(int);
    int* blocksum  = (int*)p;                p += 1024 * sizeof(int);
    int2* csr      = (int2*)p;

    // ---- CSR build ----
    hipMemsetAsync(counts, 0, (size_t)N_NODES * sizeof(int), stream);
    hist_rows<<<(NNZ + 255) / 256, 256, 0, stream>>>(adj_rows, counts);
    scan_s1<<<N_SBLOCKS, SCAN_BLOCK, 0, stream>>>(counts, blocksum);
    scan_s2<<<1, 1024, 0, stream>>>(blocksum);
    scan_s3<<<N_SBLOCKS, SCAN_BLOCK, 0, stream>>>(counts, blocksum, row_start, fill);
    csr_fill<<<(NNZ + 255) / 256, 256, 0, stream>>>(adj_rows, adj_cols, adj_vals, fill, csr);

    // ---- Layer 0 contribution into d_out ----
    gather_init<<<(2 * BATCH * 32 + 255) / 256, 256, 0, stream>>>(
        user_emb, item_emb, users, items, out);

    // ---- Layer 1: virtual concat -> buf0; accumulate selected rows ----
    spmm_concat<<<(N_NODES + 7) / 8, 256, 0, stream>>>(
        row_start, csr, user_emb, item_emb, buf0);
    gather_acc<<<(2 * BATCH * 32 + 255) / 256, 256, 0, stream>>>(
        buf0, users, items, out);

    // ---- Layer 2: buf0 -> buf1; accumulate selected rows ----
    spmm_x<<<(N_NODES + 7) / 8, 256, 0, stream>>>(
        row_start, csr, buf0, buf1);
    gather_acc<<<(2 * BATCH * 32 + 255) / 256, 256, 0, stream>>>(
        buf1, users, items, out);

    // ---- Layer 3: selective SpMM over the 8192 needed rows only ----
    spmm_sel<<<(2 * BATCH + 7) / 8, 256, 0, stream>>>(
        row_start, csr, buf1, users, items, out);
}

// Round 6
// 532.876 us; speedup vs baseline: 15.2936x; 1.0141x over previous
//
#include <hip/hip_runtime.h>
#include <hip/hip_bf16.h>

// Problem constants (match reference)
#define USER_COUNT 100000
#define ITEM_COUNT 50000
#define N_NODES    (USER_COUNT + ITEM_COUNT)   // 150000
#define EMB        128
#define N_LAYERS   3
#define NNZ        1600000
#define BATCH      4096

#define SCAN_BLOCK 256
#define N_SBLOCKS  ((N_NODES + SCAN_BLOCK - 1) / SCAN_BLOCK)   // 586

// ---------------------------------------------------------------------------
// CSR build: histogram -> 3-kernel exclusive scan -> fill
// ---------------------------------------------------------------------------
__global__ void hist_rows(const int* __restrict__ rows, int* __restrict__ counts)
{
    int e = blockIdx.x * blockDim.x + threadIdx.x;
    if (e < NNZ) atomicAdd(&counts[rows[e]], 1);
}

__global__ void scan_s1(const int* __restrict__ counts, int* __restrict__ blocksum)
{
    int i = blockIdx.x * SCAN_BLOCK + threadIdx.x;
    int v = (i < N_NODES) ? counts[i] : 0;
    #pragma unroll
    for (int off = 32; off >= 1; off >>= 1) v += __shfl_down(v, off, 64);
    __shared__ int ws[SCAN_BLOCK / 64];
    int lane = threadIdx.x & 63, wid = threadIdx.x >> 6;
    if (lane == 0) ws[wid] = v;
    __syncthreads();
    if (threadIdx.x == 0) {
        int s = 0;
        #pragma unroll
        for (int w = 0; w < SCAN_BLOCK / 64; ++w) s += ws[w];
        blocksum[blockIdx.x] = s;
    }
}

__global__ void scan_s2(int* __restrict__ blocksum)
{
    __shared__ int sm[1024];
    int t = threadIdx.x;
    int v = (t < N_SBLOCKS) ? blocksum[t] : 0;
    sm[t] = v;
    __syncthreads();
    #pragma unroll
    for (int off = 1; off < 1024; off <<= 1) {
        int tv = (t >= off) ? sm[t - off] : 0;
        __syncthreads();
        sm[t] += tv;
        __syncthreads();
    }
    if (t < N_SBLOCKS) blocksum[t] = sm[t] - v;   // exclusive
}

__global__ void scan_s3(const int* __restrict__ counts,
                        const int* __restrict__ blocksum,
                        int* __restrict__ row_start,
                        int* __restrict__ fill)
{
    __shared__ int sm[SCAN_BLOCK];
    int t = threadIdx.x;
    int i = blockIdx.x * SCAN_BLOCK + t;
    int v = (i < N_NODES) ? counts[i] : 0;
    sm[t] = v;
    __syncthreads();
    #pragma unroll
    for (int off = 1; off < SCAN_BLOCK; off <<= 1) {
        int tv = (t >= off) ? sm[t - off] : 0;
        __syncthreads();
        sm[t] += tv;
        __syncthreads();
    }
    if (i < N_NODES) {
        int excl = blocksum[blockIdx.x] + sm[t] - v;
        row_start[i] = excl;
        fill[i] = excl;
        if (i == N_NODES - 1) row_start[N_NODES] = excl + v;
    }
}

__global__ void csr_fill(const int* __restrict__ rows,
                         const int* __restrict__ cols,
                         const float* __restrict__ vals,
                         int* __restrict__ fill,
                         int2* __restrict__ csr)
{
    int e = blockIdx.x * blockDim.x + threadIdx.x;
    if (e >= NNZ) return;
    int pos = atomicAdd(&fill[rows[e]], 1);
    csr[pos] = make_int2(cols[e], __float_as_int(vals[e]));
}

// ---------------------------------------------------------------------------
// Full SpMM, dense source x. Half-wave (32 lanes x float4 = 128 features)
// per row; 8-edge unroll with clamped-index predication (8 gathers in flight).
// Block 256 = 8 half-waves = 8 rows.
// ---------------------------------------------------------------------------
__global__ void spmm_x(const int*  __restrict__ row_start,
                       const int2* __restrict__ csr,
                       const float* __restrict__ x,
                       float* __restrict__ y)
{
    int half = threadIdx.x >> 5;            // 0..7
    int r = blockIdx.x * 8 + half;
    if (r >= N_NODES) return;
    int j = (threadIdx.x & 31) * 4;
    int s = row_start[r];
    int e = row_start[r + 1];
    float4 acc = { 0.f, 0.f, 0.f, 0.f };
    for (int k = s; k < e; k += 8) {
        int i0 = k;
        int i1 = (k + 1 < e) ? k + 1 : e - 1;
        int i2 = (k + 2 < e) ? k + 2 : e - 1;
        int i3 = (k + 3 < e) ? k + 3 : e - 1;
        int i4 = (k + 4 < e) ? k + 4 : e - 1;
        int i5 = (k + 5 < e) ? k + 5 : e - 1;
        int i6 = (k + 6 < e) ? k + 6 : e - 1;
        int i7 = (k + 7 < e) ? k + 7 : e - 1;
        int2 p0 = csr[i0]; int2 p1 = csr[i1]; int2 p2 = csr[i2]; int2 p3 = csr[i3];
        int2 p4 = csr[i4]; int2 p5 = csr[i5]; int2 p6 = csr[i6]; int2 p7 = csr[i7];
        float v0 = __int_as_float(p0.y);
        float v1 = (k + 1 < e) ? __int_as_float(p1.y) : 0.f;
        float v2 = (k + 2 < e) ? __int_as_float(p2.y) : 0.f;
        float v3 = (k + 3 < e) ? __int_as_float(p3.y) : 0.f;
        float v4 = (k + 4 < e) ? __int_as_float(p4.y) : 0.f;
        float v5 = (k + 5 < e) ? __int_as_float(p5.y) : 0.f;
        float v6 = (k + 6 < e) ? __int_as_float(p6.y) : 0.f;
        float v7 = (k + 7 < e) ? __int_as_float(p7.y) : 0.f;
        float4 x0 = *(const float4*)(x + (size_t)p0.x * EMB + j);
        float4 x1 = *(const float4*)(x + (size_t)p1.x * EMB + j);
        float4 x2 = *(const float4*)(x + (size_t)p2.x * EMB + j);
        float4 x3 = *(const float4*)(x + (size_t)p3.x * EMB + j);
        float4 x4 = *(const float4*)(x + (size_t)p4.x * EMB + j);
        float4 x5 = *(const float4*)(x + (size_t)p5.x * EMB + j);
        float4 x6 = *(const float4*)(x + (size_t)p6.x * EMB + j);
        float4 x7 = *(const float4*)(x + (size_t)p7.x * EMB + j);
        acc.x += v0 * x0.x + v1 * x1.x + v2 * x2.x + v3 * x3.x
               + v4 * x4.x + v5 * x5.x + v6 * x6.x + v7 * x7.x;
        acc.y += v0 * x0.y + v1 * x1.y + v2 * x2.y + v3 * x3.y
               + v4 * x4.y + v5 * x5.y + v6 * x6.y + v7 * x7.y;
        acc.z += v0 * x0.z + v1 * x1.z + v2 * x2.z + v3 * x3.z
               + v4 * x4.z + v5 * x5.z + v6 * x6.z + v7 * x7.z;
        acc.w += v0 * x0.w + v1 * x1.w + v2 * x2.w + v3 * x3.w
               + v4 * x4.w + v5 * x5.w + v6 * x6.w + v7 * x7.w;
    }
    *(float4*)(y + (size_t)r * EMB + j) = acc;
}

// Full SpMM, virtual concat(user_emb,item_emb) source (layer 1).
__global__ void spmm_concat(const int*  __restrict__ row_start,
                            const int2* __restrict__ csr,
                            const float* __restrict__ user_emb,
                            const float* __restrict__ item_emb,
                            float* __restrict__ y)
{
    int half = threadIdx.x >> 5;
    int r = blockIdx.x * 8 + half;
    if (r >= N_NODES) return;
    int j = (threadIdx.x & 31) * 4;
    int s = row_start[r];
    int e = row_start[r + 1];
    float4 acc = { 0.f, 0.f, 0.f, 0.f };
    for (int k = s; k < e; k += 8) {
        int i0 = k;
        int i1 = (k + 1 < e) ? k + 1 : e - 1;
        int i2 = (k + 2 < e) ? k + 2 : e - 1;
        int i3 = (k + 3 < e) ? k + 3 : e - 1;
        int i4 = (k + 4 < e) ? k + 4 : e - 1;
        int i5 = (k + 5 < e) ? k + 5 : e - 1;
        int i6 = (k + 6 < e) ? k + 6 : e - 1;
        int i7 = (k + 7 < e) ? k + 7 : e - 1;
        int2 p0 = csr[i0]; int2 p1 = csr[i1]; int2 p2 = csr[i2]; int2 p3 = csr[i3];
        int2 p4 = csr[i4]; int2 p5 = csr[i5]; int2 p6 = csr[i6]; int2 p7 = csr[i7];
        float v0 = __int_as_float(p0.y);
        float v1 = (k + 1 < e) ? __int_as_float(p1.y) : 0.f;
        float v2 = (k + 2 < e) ? __int_as_float(p2.y) : 0.f;
        float v3 = (k + 3 < e) ? __int_as_float(p3.y) : 0.f;
        float v4 = (k + 4 < e) ? __int_as_float(p4.y) : 0.f;
        float v5 = (k + 5 < e) ? __int_as_float(p5.y) : 0.f;
        float v6 = (k + 6 < e) ? __int_as_float(p6.y) : 0.f;
        float v7 = (k + 7 < e) ? __int_as_float(p7.y) : 0.f;
        const float* s0 = (p0.x < USER_COUNT) ? user_emb + (size_t)p0.x * EMB
                                              : item_emb + (size_t)(p0.x - USER_COUNT) * EMB;
        const float* s1 = (p1.x < USER_COUNT) ? user_emb + (size_t)p1.x * EMB
                                              : item_emb + (size_t)(p1.x - USER_COUNT) * EMB;
        const float* s2 = (p2.x < USER_COUNT) ? user_emb + (size_t)p2.x * EMB
                                              : item_emb + (size_t)(p2.x - USER_COUNT) * EMB;
        const float* s3 = (p3.x < USER_COUNT) ? user_emb + (size_t)p3.x * EMB
                                              : item_emb + (size_t)(p3.x - USER_COUNT) * EMB;
        const float* s4 = (p4.x < USER_COUNT) ? user_emb + (size_t)p4.x * EMB
                                              : item_emb + (size_t)(p4.x - USER_COUNT) * EMB;
        const float* s5 = (p5.x < USER_COUNT) ? user_emb + (size_t)p5.x * EMB
                                              : item_emb + (size_t)(p5.x - USER_COUNT) * EMB;
        const float* s6 = (p6.x < USER_COUNT) ? user_emb + (size_t)p6.x * EMB
                                              : item_emb + (size_t)(p6.x - USER_COUNT) * EMB;
        const float* s7 = (p7.x < USER_COUNT) ? user_emb + (size_t)p7.x * EMB
                                              : item_emb + (size_t)(p7.x - USER_COUNT) * EMB;
        float4 x0 = *(const float4*)(s0 + j);
        float4 x1 = *(const float4*)(s1 + j);
        float4 x2 = *(const float4*)(s2 + j);
        float4 x3 = *(const float4*)(s3 + j);
        float4 x4 = *(const float4*)(s4 + j);
        float4 x5 = *(const float4*)(s5 + j);
        float4 x6 = *(const float4*)(s6 + j);
        float4 x7 = *(const float4*)(s7 + j);
        acc.x += v0 * x0.x + v1 * x1.x + v2 * x2.x + v3 * x3.x
               + v4 * x4.x + v5 * x5.x + v6 * x6.x + v7 * x7.x;
        acc.y += v0 * x0.y + v1 * x1.y + v2 * x2.y + v3 * x3.y
               + v4 * x4.y + v5 * x5.y + v6 * x6.y + v7 * x7.y;
        acc.z += v0 * x0.z + v1 * x1.z + v2 * x2.z + v3 * x3.z
               + v4 * x4.z + v5 * x5.z + v6 * x6.z + v7 * x7.z;
        acc.w += v0 * x0.w + v1 * x1.w + v2 * x2.w + v3 * x3.w
               + v4 * x4.w + v5 * x5.w + v6 * x6.w + v7 * x7.w;
    }
    *(float4*)(y + (size_t)r * EMB + j) = acc;
}

// ---------------------------------------------------------------------------
// Fused final kernel: half-wave per OUTPUT row b (8192 total).
// out[b] = 0.25 * ( ego0[node] + buf0[node] + buf1[node] + (A buf1)[node] )
// Single write of d_out; no read-modify-write of poisoned memory.
// ---------------------------------------------------------------------------
__global__ void spmm_final(const int*  __restrict__ row_start,
                           const int2* __restrict__ csr,
                           const float* __restrict__ buf0,
                           const float* __restrict__ buf1,
                           const float* __restrict__ user_emb,
                           const float* __restrict__ item_emb,
                           const int*   __restrict__ users,
                           const int*   __restrict__ items,
                           float* __restrict__ out)
{
    int half = threadIdx.x >> 5;
    int b = blockIdx.x * 8 + half;
    if (b >= 2 * BATCH) return;
    int node;
    const float* ego0;
    if (b < BATCH) {
        node = users[b];
        ego0 = user_emb + (size_t)node * EMB;
    } else {
        int it = items[b - BATCH];
        node = USER_COUNT + it;
        ego0 = item_emb + (size_t)it * EMB;
    }
    int j = (threadIdx.x & 31) * 4;
    int s = row_start[node];
    int e = row_start[node + 1];
    float4 acc = { 0.f, 0.f, 0.f, 0.f };
    for (int k = s; k < e; k += 4) {
        int i1 = (k + 1 < e) ? k + 1 : e - 1;
        int i2 = (k + 2 < e) ? k + 2 : e - 1;
        int i3 = (k + 3 < e) ? k + 3 : e - 1;
        int2 p0 = csr[k];
        int2 p1 = csr[i1];
        int2 p2 = csr[i2];
        int2 p3 = csr[i3];
        float v0 = __int_as_float(p0.y);
        float v1 = (k + 1 < e) ? __int_as_float(p1.y) : 0.f;
        float v2 = (k + 2 < e) ? __int_as_float(p2.y) : 0.f;
        float v3 = (k + 3 < e) ? __int_as_float(p3.y) : 0.f;
        float4 x0 = *(const float4*)(buf1 + (size_t)p0.x * EMB + j);
        float4 x1 = *(const float4*)(buf1 + (size_t)p1.x * EMB + j);
        float4 x2 = *(const float4*)(buf1 + (size_t)p2.x * EMB + j);
        float4 x3 = *(const float4*)(buf1 + (size_t)p3.x * EMB + j);
        acc.x += v0 * x0.x + v1 * x1.x + v2 * x2.x + v3 * x3.x;
        acc.y += v0 * x0.y + v1 * x1.y + v2 * x2.y + v3 * x3.y;
        acc.z += v0 * x0.z + v1 * x1.z + v2 * x2.z + v3 * x3.z;
        acc.w += v0 * x0.w + v1 * x1.w + v2 * x2.w + v3 * x3.w;
    }
    float4 a0 = *(const float4*)(ego0 + j);
    float4 a1 = *(const float4*)(buf0 + (size_t)node * EMB + j);
    float4 a2 = *(const float4*)(buf1 + (size_t)node * EMB + j);
    float4 o;
    o.x = 0.25f * (a0.x + a1.x + a2.x + acc.x);
    o.y = 0.25f * (a0.y + a1.y + a2.y + acc.y);
    o.z = 0.25f * (a0.z + a1.z + a2.z + acc.z);
    o.w = 0.25f * (a0.w + a1.w + a2.w + acc.w);
    *(float4*)(out + (size_t)b * EMB + j) = o;
}

extern "C" void kernel_launch(void* const* d_in, const int* in_sizes, int n_in,
                              void* d_out, int out_size, void* d_ws, size_t ws_size,
                              hipStream_t stream) {
    const float* user_emb = (const float*)d_in[0];
    const float* item_emb = (const float*)d_in[1];
    const float* adj_vals = (const float*)d_in[2];
    const int*   adj_rows = (const int*)d_in[3];
    const int*   adj_cols = (const int*)d_in[4];
    const int*   users    = (const int*)d_in[5];
    const int*   items    = (const int*)d_in[6];
    float* out = (float*)d_out;

    const size_t node_elems = (size_t)N_NODES * EMB;
    char* p = (char*)d_ws;
    float* buf0 = (float*)p;                 p += node_elems * sizeof(float);
    float* buf1 = (float*)p;                 p += node_elems * sizeof(float);
    int* counts    = (int*)p;                p += ((N_NODES + 3) & ~3) * sizeof(int);
    int* row_start = (int*)p;                p += ((N_NODES + 1 + 3) & ~3) * sizeof(int);
    int* fill      = (int*)p;                p += ((N_NODES + 3) & ~3) * sizeof(int);
    int* blocksum  = (int*)p;                p += 1024 * sizeof(int);
    int2* csr      = (int2*)p;

    // ---- CSR build ----
    hipMemsetAsync(counts, 0, (size_t)N_NODES * sizeof(int), stream);
    hist_rows<<<(NNZ + 255) / 256, 256, 0, stream>>>(adj_rows, counts);
    scan_s1<<<N_SBLOCKS, SCAN_BLOCK, 0, stream>>>(counts, blocksum);
    scan_s2<<<1, 1024, 0, stream>>>(blocksum);
    scan_s3<<<N_SBLOCKS, SCAN_BLOCK, 0, stream>>>(counts, blocksum, row_start, fill);
    csr_fill<<<(NNZ + 255) / 256, 256, 0, stream>>>(adj_rows, adj_cols, adj_vals, fill, csr);

    // ---- Layer 1: virtual concat -> buf0 ----
    spmm_concat<<<(N_NODES + 7) / 8, 256, 0, stream>>>(
        row_start, csr, user_emb, item_emb, buf0);

    // ---- Layer 2: buf0 -> buf1 ----
    spmm_x<<<(N_NODES + 7) / 8, 256, 0, stream>>>(
        row_start, csr, buf0, buf1);

    // ---- Fused layer 0/1/2 gather + selective layer-3 SpMM -> d_out ----
    spmm_final<<<(2 * BATCH + 7) / 8, 256, 0, stream>>>(
        row_start, csr, buf0, buf1, user_emb, item_emb, users, items, out);
}

// Round 7
// 455.826 us; speedup vs baseline: 17.8788x; 1.1690x over previous
//
#include <hip/hip_runtime.h>
#include <hip/hip_bf16.h>

// Problem constants (match reference)
#define USER_COUNT 100000
#define ITEM_COUNT 50000
#define N_NODES    (USER_COUNT + ITEM_COUNT)   // 150000
#define EMB        128
#define N_LAYERS   3
#define NNZ        1600000
#define BATCH      4096

#define SCAN_BLOCK 256
#define N_SBLOCKS  ((N_NODES + SCAN_BLOCK - 1) / SCAN_BLOCK)   // 586

typedef unsigned int  uint32;
typedef unsigned short ushort16;

// bf16 helpers: bf16 -> f32 is exact (bits << 16); f32 -> bf16 uses RNE.
__device__ __forceinline__ float bflo(uint32 p) { return __uint_as_float(p << 16); }
__device__ __forceinline__ float bfhi(uint32 p) { return __uint_as_float(p & 0xffff0000u); }
__device__ __forceinline__ uint32 bf16pair(float a, float b)
{
    uint32 ua = __float_as_uint(a);
    uint32 ub = __float_as_uint(b);
    ua = (ua + 0x7fffu + ((ua >> 16) & 1u)) >> 16;
    ub = (ub + 0x7fffu + ((ub >> 16) & 1u)) & 0xffff0000u;
    return ua | ub;
}

// ---------------------------------------------------------------------------
// Convert concat(user_emb, item_emb) fp32 -> bf16 buffer (150000 x 128).
// One thread per 8 floats: 2.4M threads; float4 x2 read, uint2 write.
// ---------------------------------------------------------------------------
__global__ void to_bf16(const float* __restrict__ user_emb,
                        const float* __restrict__ item_emb,
                        uint32* __restrict__ ego)   // ego as packed bf16 pairs
{
    size_t t = (size_t)blockIdx.x * blockDim.x + threadIdx.x;
    size_t base = t * 8;                          // float index
    if (base >= (size_t)N_NODES * EMB) return;
    const size_t user_elems = (size_t)USER_COUNT * EMB;
    const float* src = (base < user_elems) ? user_emb + base
                                           : item_emb + (base - user_elems);
    float4 a = *(const float4*)(src);
    float4 b = *(const float4*)(src + 4);
    uint32* dst = ego + base / 2;                 // 2 floats per uint32
    dst[0] = bf16pair(a.x, a.y);
    dst[1] = bf16pair(a.z, a.w);
    dst[2] = bf16pair(b.x, b.y);
    dst[3] = bf16pair(b.z, b.w);
}

// ---------------------------------------------------------------------------
// CSR build: histogram -> 3-kernel exclusive scan -> fill  (4 edges/thread)
// ---------------------------------------------------------------------------
__global__ void hist_rows(const int* __restrict__ rows, int* __restrict__ counts)
{
    int t = blockIdx.x * blockDim.x + threadIdx.x;
    int e = t * 4;
    if (e >= NNZ) return;
    int4 r = *(const int4*)(rows + e);
    atomicAdd(&counts[r.x], 1);
    atomicAdd(&counts[r.y], 1);
    atomicAdd(&counts[r.z], 1);
    atomicAdd(&counts[r.w], 1);
}

__global__ void scan_s1(const int* __restrict__ counts, int* __restrict__ blocksum)
{
    int i = blockIdx.x * SCAN_BLOCK + threadIdx.x;
    int v = (i < N_NODES) ? counts[i] : 0;
    #pragma unroll
    for (int off = 32; off >= 1; off >>= 1) v += __shfl_down(v, off, 64);
    __shared__ int ws[SCAN_BLOCK / 64];
    int lane = threadIdx.x & 63, wid = threadIdx.x >> 6;
    if (lane == 0) ws[wid] = v;
    __syncthreads();
    if (threadIdx.x == 0) {
        int s = 0;
        #pragma unroll
        for (int w = 0; w < SCAN_BLOCK / 64; ++w) s += ws[w];
        blocksum[blockIdx.x] = s;
    }
}

__global__ void scan_s2(int* __restrict__ blocksum)
{
    __shared__ int sm[1024];
    int t = threadIdx.x;
    int v = (t < N_SBLOCKS) ? blocksum[t] : 0;
    sm[t] = v;
    __syncthreads();
    #pragma unroll
    for (int off = 1; off < 1024; off <<= 1) {
        int tv = (t >= off) ? sm[t - off] : 0;
        __syncthreads();
        sm[t] += tv;
        __syncthreads();
    }
    if (t < N_SBLOCKS) blocksum[t] = sm[t] - v;   // exclusive
}

__global__ void scan_s3(const int* __restrict__ counts,
                        const int* __restrict__ blocksum,
                        int* __restrict__ row_start,
                        int* __restrict__ fill)
{
    __shared__ int sm[SCAN_BLOCK];
    int t = threadIdx.x;
    int i = blockIdx.x * SCAN_BLOCK + t;
    int v = (i < N_NODES) ? counts[i] : 0;
    sm[t] = v;
    __syncthreads();
    #pragma unroll
    for (int off = 1; off < SCAN_BLOCK; off <<= 1) {
        int tv = (t >= off) ? sm[t - off] : 0;
        __syncthreads();
        sm[t] += tv;
        __syncthreads();
    }
    if (i < N_NODES) {
        int excl = blocksum[blockIdx.x] + sm[t] - v;
        row_start[i] = excl;
        fill[i] = excl;
        if (i == N_NODES - 1) row_start[N_NODES] = excl + v;
    }
}

__global__ void csr_fill(const int* __restrict__ rows,
                         const int* __restrict__ cols,
                         const float* __restrict__ vals,
                         int* __restrict__ fill,
                         int2* __restrict__ csr)
{
    int t = blockIdx.x * blockDim.x + threadIdx.x;
    int e = t * 4;
    if (e >= NNZ) return;
    int4   r = *(const int4*)(rows + e);
    int4   c = *(const int4*)(cols + e);
    float4 v = *(const float4*)(vals + e);
    int p0 = atomicAdd(&fill[r.x], 1);
    int p1 = atomicAdd(&fill[r.y], 1);
    int p2 = atomicAdd(&fill[r.z], 1);
    int p3 = atomicAdd(&fill[r.w], 1);
    csr[p0] = make_int2(c.x, __float_as_int(v.x));
    csr[p1] = make_int2(c.y, __float_as_int(v.y));
    csr[p2] = make_int2(c.z, __float_as_int(v.z));
    csr[p3] = make_int2(c.w, __float_as_int(v.w));
}

// ---------------------------------------------------------------------------
// SpMM over bf16 source/dest. Half-wave (32 lanes x 4 features via uint2)
// per row; 4-edge unroll with clamped-index predication. fp32 accumulate.
// x,y are packed bf16-pair buffers: row r starts at (r*EMB/2) uint32s.
// ---------------------------------------------------------------------------
__global__ __launch_bounds__(256, 8)
void spmm_bf16(const int*  __restrict__ row_start,
               const int2* __restrict__ csr,
               const uint32* __restrict__ x,
               uint32* __restrict__ y)
{
    int half = threadIdx.x >> 5;            // 0..7
    int r = blockIdx.x * 8 + half;
    if (r >= N_NODES) return;
    int j = (threadIdx.x & 31) * 2;         // uint32 (bf16-pair) offset in row
    int s = row_start[r];
    int e = row_start[r + 1];
    float4 acc = { 0.f, 0.f, 0.f, 0.f };
    for (int k = s; k < e; k += 4) {
        int i1 = (k + 1 < e) ? k + 1 : e - 1;
        int i2 = (k + 2 < e) ? k + 2 : e - 1;
        int i3 = (k + 3 < e) ? k + 3 : e - 1;
        int2 p0 = csr[k];
        int2 p1 = csr[i1];
        int2 p2 = csr[i2];
        int2 p3 = csr[i3];
        float v0 = __int_as_float(p0.y);
        float v1 = (k + 1 < e) ? __int_as_float(p1.y) : 0.f;
        float v2 = (k + 2 < e) ? __int_as_float(p2.y) : 0.f;
        float v3 = (k + 3 < e) ? __int_as_float(p3.y) : 0.f;
        uint2 g0 = *(const uint2*)(x + (size_t)p0.x * (EMB / 2) + j);
        uint2 g1 = *(const uint2*)(x + (size_t)p1.x * (EMB / 2) + j);
        uint2 g2 = *(const uint2*)(x + (size_t)p2.x * (EMB / 2) + j);
        uint2 g3 = *(const uint2*)(x + (size_t)p3.x * (EMB / 2) + j);
        acc.x += v0 * bflo(g0.x) + v1 * bflo(g1.x) + v2 * bflo(g2.x) + v3 * bflo(g3.x);
        acc.y += v0 * bfhi(g0.x) + v1 * bfhi(g1.x) + v2 * bfhi(g2.x) + v3 * bfhi(g3.x);
        acc.z += v0 * bflo(g0.y) + v1 * bflo(g1.y) + v2 * bflo(g2.y) + v3 * bflo(g3.y);
        acc.w += v0 * bfhi(g0.y) + v1 * bfhi(g1.y) + v2 * bfhi(g2.y) + v3 * bfhi(g3.y);
    }
    uint2 o;
    o.x = bf16pair(acc.x, acc.y);
    o.y = bf16pair(acc.z, acc.w);
    *(uint2*)(y + (size_t)r * (EMB / 2) + j) = o;
}

// ---------------------------------------------------------------------------
// Fused final kernel: half-wave per OUTPUT row b (8192 total).
// out[b] = 0.25 * ( ego_fp32[node] + buf0[node] + buf1[node] + (A buf1)[node] )
// ego term read from fp32 originals (keeps the largest direct term exact).
// ---------------------------------------------------------------------------
__global__ void spmm_final(const int*  __restrict__ row_start,
                           const int2* __restrict__ csr,
                           const uint32* __restrict__ buf0,
                           const uint32* __restrict__ buf1,
                           const float* __restrict__ user_emb,
                           const float* __restrict__ item_emb,
                           const int*   __restrict__ users,
                           const int*   __restrict__ items,
                           float* __restrict__ out)
{
    int half = threadIdx.x >> 5;
    int b = blockIdx.x * 8 + half;
    if (b >= 2 * BATCH) return;
    int node;
    const float* ego0;
    if (b < BATCH) {
        node = users[b];
        ego0 = user_emb + (size_t)node * EMB;
    } else {
        int it = items[b - BATCH];
        node = USER_COUNT + it;
        ego0 = item_emb + (size_t)it * EMB;
    }
    int j2 = (threadIdx.x & 31) * 2;        // uint32 offset (bf16 pairs)
    int j4 = (threadIdx.x & 31) * 4;        // float offset
    int s = row_start[node];
    int e = row_start[node + 1];
    float4 acc = { 0.f, 0.f, 0.f, 0.f };
    for (int k = s; k < e; k += 4) {
        int i1 = (k + 1 < e) ? k + 1 : e - 1;
        int i2 = (k + 2 < e) ? k + 2 : e - 1;
        int i3 = (k + 3 < e) ? k + 3 : e - 1;
        int2 p0 = csr[k];
        int2 p1 = csr[i1];
        int2 p2 = csr[i2];
        int2 p3 = csr[i3];
        float v0 = __int_as_float(p0.y);
        float v1 = (k + 1 < e) ? __int_as_float(p1.y) : 0.f;
        float v2 = (k + 2 < e) ? __int_as_float(p2.y) : 0.f;
        float v3 = (k + 3 < e) ? __int_as_float(p3.y) : 0.f;
        uint2 g0 = *(const uint2*)(buf1 + (size_t)p0.x * (EMB / 2) + j2);
        uint2 g1 = *(const uint2*)(buf1 + (size_t)p1.x * (EMB / 2) + j2);
        uint2 g2 = *(const uint2*)(buf1 + (size_t)p2.x * (EMB / 2) + j2);
        uint2 g3 = *(const uint2*)(buf1 + (size_t)p3.x * (EMB / 2) + j2);
        acc.x += v0 * bflo(g0.x) + v1 * bflo(g1.x) + v2 * bflo(g2.x) + v3 * bflo(g3.x);
        acc.y += v0 * bfhi(g0.x) + v1 * bfhi(g1.x) + v2 * bfhi(g2.x) + v3 * bfhi(g3.x);
        acc.z += v0 * bflo(g0.y) + v1 * bflo(g1.y) + v2 * bflo(g2.y) + v3 * bflo(g3.y);
        acc.w += v0 * bfhi(g0.y) + v1 * bfhi(g1.y) + v2 * bfhi(g2.y) + v3 * bfhi(g3.y);
    }
    float4 a0 = *(const float4*)(ego0 + j4);
    uint2 b0 = *(const uint2*)(buf0 + (size_t)node * (EMB / 2) + j2);
    uint2 b1 = *(const uint2*)(buf1 + (size_t)node * (EMB / 2) + j2);
    float4 o;
    o.x = 0.25f * (a0.x + bflo(b0.x) + bflo(b1.x) + acc.x);
    o.y = 0.25f * (a0.y + bfhi(b0.x) + bfhi(b1.x) + acc.y);
    o.z = 0.25f * (a0.z + bflo(b0.y) + bflo(b1.y) + acc.z);
    o.w = 0.25f * (a0.w + bfhi(b0.y) + bfhi(b1.y) + acc.w);
    *(float4*)(out + (size_t)b * EMB + j4) = o;
}

extern "C" void kernel_launch(void* const* d_in, const int* in_sizes, int n_in,
                              void* d_out, int out_size, void* d_ws, size_t ws_size,
                              hipStream_t stream) {
    const float* user_emb = (const float*)d_in[0];
    const float* item_emb = (const float*)d_in[1];
    const float* adj_vals = (const float*)d_in[2];
    const int*   adj_rows = (const int*)d_in[3];
    const int*   adj_cols = (const int*)d_in[4];
    const int*   users    = (const int*)d_in[5];
    const int*   items    = (const int*)d_in[6];
    float* out = (float*)d_out;

    // Workspace layout:
    //   ego, buf0, buf1 : N_NODES*EMB/2 uint32 (38.4 MB each, packed bf16)
    //   counts, row_start, fill, blocksum, csr
    const size_t node_pairs = (size_t)N_NODES * (EMB / 2);
    char* p = (char*)d_ws;
    uint32* ego  = (uint32*)p;               p += node_pairs * sizeof(uint32);
    uint32* buf0 = (uint32*)p;               p += node_pairs * sizeof(uint32);
    uint32* buf1 = (uint32*)p;               p += node_pairs * sizeof(uint32);
    int* counts    = (int*)p;                p += ((N_NODES + 3) & ~3) * sizeof(int);
    int* row_start = (int*)p;                p += ((N_NODES + 1 + 3) & ~3) * sizeof(int);
    int* fill      = (int*)p;                p += ((N_NODES + 3) & ~3) * sizeof(int);
    int* blocksum  = (int*)p;                p += 1024 * sizeof(int);
    int2* csr      = (int2*)p;

    // ---- ego fp32 -> bf16 (independent of CSR build) ----
    {
        size_t total = ((size_t)N_NODES * EMB) / 8;    // threads
        to_bf16<<<(int)((total + 255) / 256), 256, 0, stream>>>(user_emb, item_emb, ego);
    }

    // ---- CSR build ----
    hipMemsetAsync(counts, 0, (size_t)N_NODES * sizeof(int), stream);
    hist_rows<<<(NNZ / 4 + 255) / 256, 256, 0, stream>>>(adj_rows, counts);
    scan_s1<<<N_SBLOCKS, SCAN_BLOCK, 0, stream>>>(counts, blocksum);
    scan_s2<<<1, 1024, 0, stream>>>(blocksum);
    scan_s3<<<N_SBLOCKS, SCAN_BLOCK, 0, stream>>>(counts, blocksum, row_start, fill);
    csr_fill<<<(NNZ / 4 + 255) / 256, 256, 0, stream>>>(adj_rows, adj_cols, adj_vals, fill, csr);

    // ---- Layer 1: ego -> buf0 ----
    spmm_bf16<<<(N_NODES + 7) / 8, 256, 0, stream>>>(row_start, csr, ego, buf0);

    // ---- Layer 2: buf0 -> buf1 ----
    spmm_bf16<<<(N_NODES + 7) / 8, 256, 0, stream>>>(row_start, csr, buf0, buf1);

    // ---- Fused gather of layers 0..2 + selective layer-3 SpMM -> d_out ----
    spmm_final<<<(2 * BATCH + 7) / 8, 256, 0, stream>>>(
        row_start, csr, buf0, buf1, user_emb, item_emb, users, items, out);
}